// Round 9
// baseline (14682.764 us; speedup 1.0000x reference)
//
#include <hip/hip_runtime.h>
#include <stdint.h>
#include <math.h>

#define T_STEPS 1000

typedef __attribute__((ext_vector_type(4))) float f32x4;
typedef __attribute__((ext_vector_type(8))) _Float16 f16x8;
typedef __attribute__((ext_vector_type(4))) int i32x4;

#define C_2M11 4.8828125e-4f         // 2^-11
#define C_2M22 2.384185791015625e-7f // 2^-22
#define F16_MINNORM 6.103515625e-05f

#define VMCNT0() asm volatile("s_waitcnt vmcnt(0)" ::: "memory")
#define DEP8(x)  asm volatile("" : "+v"(x))

__device__ __forceinline__ void split2h(float v, _Float16& hi, _Float16& lo) {
    float av = fabsf(v);
    _Float16 h = (av < F16_MINNORM) ? (_Float16)0.0f : (_Float16)v;
    float r = v - (float)h;
    hi = h;
    lo = (_Float16)(r * 2048.0f);
}
__device__ __forceinline__ short f2s(_Float16 h) {
    union { _Float16 h; short s; } u; u.h = h; return u.s;
}

// ---- MALL (device coherence point) ops — proven in round 6 ----
__device__ __forceinline__ f16x8 coh_load8h(const short* p) {
    union { i32x4 i; f16x8 h; } u;
    asm volatile("global_load_dwordx4 %0, %1, off sc0 sc1" : "=v"(u.i) : "v"(p) : "memory");
    return u.h;
}
__device__ __forceinline__ f32x4 coh_load4f(const float* p) {
    f32x4 v;
    asm volatile("global_load_dwordx4 %0, %1, off sc0 sc1" : "=v"(v) : "v"(p) : "memory");
    return v;
}
__device__ __forceinline__ void coh_store_s(short* p, short v) {
    int iv = (int)(unsigned short)v;
    asm volatile("global_store_short %0, %1, off sc0 sc1" :: "v"(p), "v"(iv) : "memory");
}
__device__ __forceinline__ void coh_store4f(float* p, f32x4 v) {
    asm volatile("global_store_dwordx4 %0, %1, off sc0 sc1" :: "v"(p), "v"(v) : "memory");
}
__device__ __forceinline__ void coh_store_i(int* p, int v) {
    asm volatile("global_store_dword %0, %1, off sc0 sc1" :: "v"(p), "v"(v) : "memory");
}
__device__ __forceinline__ int coh_load_i_wait(const int* p) {
    int v;
    asm volatile("global_load_dword %0, %1, off sc0 sc1\n\ts_waitcnt vmcnt(0)"
                 : "=v"(v) : "v"(p) : "memory");
    return v;
}

// ---- flag-line barrier (pure MALL, no atomics) ----
// flags: 16 ints in one 64B line per row-group. Block cg stores monotone seq
// to flags[cg] (write-through sc0 sc1); all 64 lanes poll with one coalesced
// sc0 sc1 load (lane j reads flags[j&15]); proceed when all >= seq.
// Data stores are drained (vmcnt0) before the flag store issues, so a visible
// flag implies visible data at the coherence point (round-6-proven ordering).
__device__ __forceinline__ void fbar_sync(int* flags, int cg, int lane, int seq) {
    VMCNT0();
    if (lane == 0) coh_store_i(&flags[cg], seq);
    const int* myf = &flags[lane & 15];
    int spins = 0;
    int v;
    do {
        v = coh_load_i_wait(myf);
        if (++spins > (1 << 17)) break;  // hang guard; protocol is sound, never fires
    } while (__any(v < seq));
}

#define MFMAH(a, b, c) __builtin_amdgcn_mfma_f32_16x16x32_f16((a), (b), (c), 0, 0, 0)

// ---------------- prep kernels ----------------
__global__ void scalars_kernel(float* As, float* Bc, float* Dc) {
    if (threadIdx.x == 0 && blockIdx.x == 0) {
        float acp = 1.0f, ac_prev = 1.0f;
        for (int t = 0; t < T_STEPS; ++t) {
            float beta = (float)(1.0e-4 + (double)t * ((0.02 - 1.0e-4) / 999.0));
            acp = acp * (1.0f - beta);
            int i = (T_STEPS - 1) - t;
            As[i] = sqrtf(acp);
            Bc[i] = sqrtf(1.0f - acp);
            Dc[i] = sqrtf(1.0f - ac_prev) + sqrtf(beta);
            ac_prev = acp;
        }
    }
}
__global__ void initflags_kernel(int* p, int n) {
    int i = blockIdx.x * 64 + threadIdx.x;
    if (i < n) coh_store_i(p + i, 0);
}
__global__ __launch_bounds__(256) void feats_kernel(const float* tw1, const float* tb1, float* s) {
    int idx = blockIdx.x * 256 + threadIdx.x;
    if (idx < T_STEPS * 512) {
        int t = idx >> 9, m = idx & 511;
        float a = (float)t * tw1[m] + tb1[m];
        s[idx] = a / (1.0f + expf(-a));
    }
}
__global__ __launch_bounds__(256) void gemm_kernel(const float* A, const float* B,
                                                   const float* bias, float* C, int M) {
    __shared__ float Asm[16][68];
    __shared__ float Bsm[16][68];
    int tx = threadIdx.x & 15, ty = threadIdx.x >> 4;
    int m0 = blockIdx.x * 64, n0 = blockIdx.y * 64;
    float acc[4][4] = {};
    for (int k0 = 0; k0 < 512; k0 += 16) {
        for (int l = 0; l < 4; ++l) {
            int e = threadIdx.x + l * 256;
            int mm = e >> 4, kk = e & 15;
            Asm[kk][mm] = (m0 + mm < M) ? A[(size_t)(m0 + mm) * 512 + k0 + kk] : 0.0f;
            int nn = e & 63, kk2 = e >> 6;
            Bsm[kk2][nn] = B[(size_t)(k0 + kk2) * 512 + n0 + nn];
        }
        __syncthreads();
        for (int kk = 0; kk < 16; ++kk) {
            float a[4], b[4];
            for (int i = 0; i < 4; ++i) a[i] = Asm[kk][ty * 4 + i];
            for (int j = 0; j < 4; ++j) b[j] = Bsm[kk][tx * 4 + j];
            for (int i = 0; i < 4; ++i)
                for (int j = 0; j < 4; ++j) acc[i][j] += a[i] * b[j];
        }
        __syncthreads();
    }
    for (int i = 0; i < 4; ++i) {
        int m = m0 + ty * 4 + i;
        if (m < M)
            for (int j = 0; j < 4; ++j) {
                int n = n0 + tx * 4 + j;
                C[(size_t)m * 512 + n] = acc[i][j] + bias[n];
            }
    }
}
__global__ __launch_bounds__(256) void tpack_kernel(const float* w, short* ph, short* pl) {
    int p = blockIdx.x * 256 + threadIdx.x;
    if (p < 512 * 512) {
        int chunk = p >> 9, inch = p & 511;
        int n = (chunk >> 4) * 16 + (inch >> 5);
        int k = (chunk & 15) * 32 + (inch & 31);
        float v = w[(size_t)k * 512 + n];
        _Float16 hi, lo;
        split2h(v, hi, lo);
        ph[p] = f2s(hi);
        pl[p] = f2s(lo);
    }
}

// ---------------- main loop: 256 blocks x 64 threads (round-6 structure) ----------------
__global__ __launch_bounds__(64, 1) void diffusion_main(
    const float* x0,
    const short* w1h_, const short* w1l_,
    const short* w2h_, const short* w2l_,
    short* xgh, short* xgl, short* hgh, short* hgl,
    float* hid_d, float* hid_e, int* flagsAll,
    const float* tep, const float* nb2,
    const float* As, const float* Bc, const float* Dc,
    const float* dw1, const float* db1, const float* dw2, const float* db2,
    const float* ew1, const float* eb1, const float* ew2, const float* eb2,
    float* out) {

    __shared__ short wlds[32768];  // [0,16384): W1hi slice, [16384,32768): W2hi slice

    const int bid = blockIdx.x;
    const int rg = ((bid & 7) << 1) | (bid >> 7);
    const int cg = (bid >> 3) & 15;
    const int lane = threadIdx.x;
    const int l15 = lane & 15, lg = lane >> 4;
    const int aoff = l15 * 32 + lg * 8;
    const int b0 = rg * 16;
    int* flags = flagsAll + rg * 16;   // one 64B line per row-group

    const short* w1hS = w1h_ + (size_t)cg * 16384;
    const short* w1lS = w1l_ + (size_t)cg * 16384;
    const short* w2hS = w2h_ + (size_t)cg * 16384;
    const short* w2lS = w2l_ + (size_t)cg * 16384;

    // one-time: hi-limb weight slices into LDS (plain cached loads)
    {
        const i32x4* s1 = (const i32x4*)w1hS;
        const i32x4* s2 = (const i32x4*)w2hS;
        i32x4* d = (i32x4*)wlds;
        for (int e = lane; e < 2048; e += 64) d[e] = s1[e];
        for (int e = lane; e < 2048; e += 64) d[2048 + e] = s2[e];
    }
    __syncthreads();

    short* xghR = xgh + rg * 8192;
    short* xglR = xgl + rg * 8192;
    short* hghR = hgh + rg * 8192;
    short* hglR = hgl + rg * 8192;

    // init x slice + publish (coherence-point stores)
    float xr[2][4], nb2r[2];
    for (int nt = 0; nt < 2; ++nt) {
        int n = cg * 32 + nt * 16 + l15;
        nb2r[nt] = nb2[n];
        for (int r = 0; r < 4; ++r) {
            float v = x0[(size_t)(b0 + lg * 4 + r) * 512 + n];
            xr[nt][r] = v;
            _Float16 hi, lo;
            split2h(v, hi, lo);
            int o = cg * 512 + (lg * 4 + r) * 32 + nt * 16 + l15;
            coh_store_s(xghR + o, f2s(hi));
            coh_store_s(xglR + o, f2s(lo));
        }
    }
    int seq = 1;
    fbar_sync(flags, cg, lane, seq); ++seq;

#pragma unroll 1
    for (int i = 0; i < T_STEPS; ++i) {
        const int t = (T_STEPS - 1) - i;
        float tep_r[2];
        tep_r[0] = tep[(size_t)t * 512 + cg * 32 + l15];
        tep_r[1] = tep[(size_t)t * 512 + cg * 32 + 16 + l15];
        const float a_s = As[i], bc = Bc[i], dc = Dc[i];

        // ---- GEMM1: h_slice = relu(x @ W1slice + tep) ----
        f32x4 a0[2], a1[2], a2[2];
#pragma unroll
        for (int nt = 0; nt < 2; ++nt) {
            a0[nt] = (f32x4){0.f, 0.f, 0.f, 0.f};
            a1[nt] = (f32x4){0.f, 0.f, 0.f, 0.f};
            a2[nt] = (f32x4){0.f, 0.f, 0.f, 0.f};
        }
        {
            f16x8 xa_h[16], xa_l[16];
#pragma unroll
            for (int kb = 0; kb < 16; ++kb) {
                xa_h[kb] = coh_load8h(xghR + kb * 512 + aoff);
                xa_l[kb] = coh_load8h(xglR + kb * 512 + aoff);
            }
            VMCNT0();
#pragma unroll
            for (int kb = 0; kb < 16; ++kb) { DEP8(xa_h[kb]); DEP8(xa_l[kb]); }
#pragma unroll
            for (int kb = 0; kb < 16; ++kb) {
                f16x8 ah = xa_h[kb], al = xa_l[kb];
#pragma unroll
                for (int nt = 0; nt < 2; ++nt) {
                    f16x8 bh = *(const f16x8*)(&wlds[(nt * 16 + kb) * 512 + aoff]);
                    f16x8 bl = *(const f16x8*)(w1lS + (nt * 16 + kb) * 512 + aoff);
                    a0[nt] = MFMAH(ah, bh, a0[nt]);
                    a1[nt] = MFMAH(ah, bl, a1[nt]);
                    a1[nt] = MFMAH(al, bh, a1[nt]);
                    a2[nt] = MFMAH(al, bl, a2[nt]);
                }
            }
        }
#pragma unroll
        for (int nt = 0; nt < 2; ++nt)
#pragma unroll
            for (int r = 0; r < 4; ++r) {
                float hv = a0[nt][r] + a1[nt][r] * C_2M11 + a2[nt][r] * C_2M22 + tep_r[nt];
                hv = hv > 0.f ? hv : 0.f;
                _Float16 hi, lo;
                split2h(hv, hi, lo);
                int o = cg * 512 + (lg * 4 + r) * 32 + nt * 16 + l15;
                coh_store_s(hghR + o, f2s(hi));
                coh_store_s(hglR + o, f2s(lo));
            }
        fbar_sync(flags, cg, lane, seq); ++seq;

        // ---- GEMM2: eps_slice = h @ W2slice + nb2; x update ----
#pragma unroll
        for (int nt = 0; nt < 2; ++nt) {
            a0[nt] = (f32x4){0.f, 0.f, 0.f, 0.f};
            a1[nt] = (f32x4){0.f, 0.f, 0.f, 0.f};
            a2[nt] = (f32x4){0.f, 0.f, 0.f, 0.f};
        }
        {
            f16x8 xa_h[16], xa_l[16];
#pragma unroll
            for (int kb = 0; kb < 16; ++kb) {
                xa_h[kb] = coh_load8h(hghR + kb * 512 + aoff);
                xa_l[kb] = coh_load8h(hglR + kb * 512 + aoff);
            }
            VMCNT0();
#pragma unroll
            for (int kb = 0; kb < 16; ++kb) { DEP8(xa_h[kb]); DEP8(xa_l[kb]); }
#pragma unroll
            for (int kb = 0; kb < 16; ++kb) {
                f16x8 ah = xa_h[kb], al = xa_l[kb];
#pragma unroll
                for (int nt = 0; nt < 2; ++nt) {
                    f16x8 bh = *(const f16x8*)(&wlds[16384 + (nt * 16 + kb) * 512 + aoff]);
                    f16x8 bl = *(const f16x8*)(w2lS + (nt * 16 + kb) * 512 + aoff);
                    a0[nt] = MFMAH(ah, bh, a0[nt]);
                    a1[nt] = MFMAH(ah, bl, a1[nt]);
                    a1[nt] = MFMAH(al, bh, a1[nt]);
                    a2[nt] = MFMAH(al, bl, a2[nt]);
                }
            }
        }
#pragma unroll
        for (int nt = 0; nt < 2; ++nt)
#pragma unroll
            for (int r = 0; r < 4; ++r) {
                float eps = a0[nt][r] + a1[nt][r] * C_2M11 + a2[nt][r] * C_2M22 + nb2r[nt];
                float xv = (xr[nt][r] - bc * eps) / a_s + dc * eps;
                xv = fminf(fmaxf(xv, -1000.0f), 1000.0f);
                xr[nt][r] = xv;
                _Float16 hi, lo;
                split2h(xv, hi, lo);
                int o = cg * 512 + (lg * 4 + r) * 32 + nt * 16 + l15;
                coh_store_s(xghR + o, f2s(hi));
                coh_store_s(xglR + o, f2s(lo));
            }
        fbar_sync(flags, cg, lane, seq); ++seq;
    }

    // ---- epilogue ----
#pragma unroll
    for (int nt = 0; nt < 2; ++nt)
#pragma unroll
        for (int r = 0; r < 4; ++r)
            out[(size_t)(b0 + lg * 4 + r) * 515 + 3 + cg * 32 + nt * 16 + l15] = xr[nt][r];

    // head hidden slices: lane -> row m=l15, cols cbase..cbase+3
    {
        const int cbase = cg * 16 + lg * 4;
        float a4d[4] = {0.f, 0.f, 0.f, 0.f};
        float a4e[4] = {0.f, 0.f, 0.f, 0.f};
#pragma unroll 1
        for (int kb = 0; kb < 16; ++kb) {
            f16x8 xh8[4], xl8[4];
#pragma unroll
            for (int d = 0; d < 4; ++d) {
                xh8[d] = coh_load8h(xghR + kb * 512 + l15 * 32 + d * 8);
                xl8[d] = coh_load8h(xglR + kb * 512 + l15 * 32 + d * 8);
            }
            VMCNT0();
#pragma unroll
            for (int d = 0; d < 4; ++d) { DEP8(xh8[d]); DEP8(xl8[d]); }
#pragma unroll
            for (int d = 0; d < 4; ++d)
#pragma unroll
                for (int jj = 0; jj < 8; ++jj) {
                    float xv = (float)xh8[d][jj] + (float)xl8[d][jj] * C_2M11;
                    int k = kb * 32 + d * 8 + jj;
                    f32x4 wd = *(const f32x4*)(dw1 + (size_t)k * 256 + cbase);
                    f32x4 we = *(const f32x4*)(ew1 + (size_t)k * 256 + cbase);
#pragma unroll
                    for (int j = 0; j < 4; ++j) {
                        a4d[j] += xv * wd[j];
                        a4e[j] += xv * we[j];
                    }
                }
        }
        f32x4 hd, he;
#pragma unroll
        for (int j = 0; j < 4; ++j) {
            float hdv = a4d[j] + db1[cbase + j];
            float hev = a4e[j] + eb1[cbase + j];
            hd[j] = hdv > 0.f ? hdv : 0.f;
            he[j] = hev > 0.f ? hev : 0.f;
        }
        coh_store4f(hid_d + rg * 4096 + l15 * 256 + cbase, hd);
        coh_store4f(hid_e + rg * 4096 + l15 * 256 + cbase, he);
    }
    fbar_sync(flags, cg, lane, seq); ++seq;

    if (cg == 0) {
        f32x4 hd4[16], he4[16];
#pragma unroll
        for (int q = 0; q < 16; ++q) {
            hd4[q] = coh_load4f(hid_d + rg * 4096 + l15 * 256 + lg * 64 + q * 4);
            he4[q] = coh_load4f(hid_e + rg * 4096 + l15 * 256 + lg * 64 + q * 4);
        }
        VMCNT0();
#pragma unroll
        for (int q = 0; q < 16; ++q) { DEP8(hd4[q]); DEP8(he4[q]); }
        float sd = 0.f, se1 = 0.f, se2 = 0.f;
#pragma unroll
        for (int q = 0; q < 16; ++q)
#pragma unroll
            for (int j = 0; j < 4; ++j) {
                int c = lg * 64 + q * 4 + j;
                sd += hd4[q][j] * dw2[c];
                se1 += he4[q][j] * ew2[2 * c];
                se2 += he4[q][j] * ew2[2 * c + 1];
            }
        sd += __shfl_xor(sd, 16); sd += __shfl_xor(sd, 32);
        se1 += __shfl_xor(se1, 16); se1 += __shfl_xor(se1, 32);
        se2 += __shfl_xor(se2, 16); se2 += __shfl_xor(se2, 32);
        if (lg == 0) {
            out[(size_t)(b0 + l15) * 515 + 0] = sd + db2[0];
            out[(size_t)(b0 + l15) * 515 + 1] = se1 + eb2[0];
            out[(size_t)(b0 + l15) * 515 + 2] = se2 + eb2[1];
        }
    }
}

extern "C" void kernel_launch(void* const* d_in, const int* in_sizes, int n_in,
                              void* d_out, int out_size, void* d_ws, size_t ws_size,
                              hipStream_t stream) {
    const float* x0  = (const float*)d_in[0];
    const float* tw1 = (const float*)d_in[1];
    const float* tb1 = (const float*)d_in[2];
    const float* tw2 = (const float*)d_in[3];
    const float* tb2 = (const float*)d_in[4];
    const float* nw1 = (const float*)d_in[5];
    const float* nb1 = (const float*)d_in[6];
    const float* nw2 = (const float*)d_in[7];
    const float* nb2 = (const float*)d_in[8];
    const float* dw1 = (const float*)d_in[9];
    const float* db1 = (const float*)d_in[10];
    const float* dw2 = (const float*)d_in[11];
    const float* db2 = (const float*)d_in[12];
    const float* ew1 = (const float*)d_in[13];
    const float* eb1 = (const float*)d_in[14];
    const float* ew2 = (const float*)d_in[15];
    const float* eb2 = (const float*)d_in[16];
    float* out = (float*)d_out;

    float* ws    = (float*)d_ws;
    float* sfeat = ws;                   // 512000 f
    float* te    = sfeat + 512000;
    float* tep   = te + 512000;
    float* Asv   = tep + 512000;         // 1024 f each
    float* Bcv   = Asv + 1024;
    float* Dcv   = Bcv + 1024;
    short* w1h   = (short*)(Dcv + 1024); // 4 planes x 262144 shorts
    short* w1l   = w1h + 262144;
    short* w2h   = w1l + 262144;
    short* w2l   = w2h + 262144;
    short* xghp  = w2l + 262144;         // 4 exchange planes x 131072 shorts
    short* xglp  = xghp + 131072;
    short* hghp  = xglp + 131072;
    short* hglp  = hghp + 131072;
    float* hid_d = (float*)(hglp + 131072); // 65536 f each
    float* hid_e = hid_d + 65536;
    int*   flagsAll = (int*)(hid_e + 65536); // 256 ints (16 rgs x 16 flags, 64B/line)

    hipLaunchKernelGGL(scalars_kernel, dim3(1), dim3(64), 0, stream, Asv, Bcv, Dcv);
    hipLaunchKernelGGL(initflags_kernel, dim3(4), dim3(64), 0, stream, flagsAll, 256);
    hipLaunchKernelGGL(feats_kernel, dim3(2000), dim3(256), 0, stream, tw1, tb1, sfeat);
    hipLaunchKernelGGL(gemm_kernel, dim3(16, 8), dim3(256), 0, stream, sfeat, tw2, tb2, te, 1000);
    hipLaunchKernelGGL(gemm_kernel, dim3(16, 8), dim3(256), 0, stream, te, nw1 + 512 * 512, nb1, tep, 1000);
    hipLaunchKernelGGL(tpack_kernel, dim3(1024), dim3(256), 0, stream, nw1, w1h, w1l);
    hipLaunchKernelGGL(tpack_kernel, dim3(1024), dim3(256), 0, stream, nw2, w2h, w2l);
    hipLaunchKernelGGL(diffusion_main, dim3(256), dim3(64), 0, stream,
                       x0, w1h, w1l, w2h, w2l,
                       xghp, xglp, hghp, hglp, hid_d, hid_e, flagsAll,
                       tep, nb2, Asv, Bcv, Dcv,
                       dw1, db1, dw2, db2, ew1, eb1, ew2, eb2, out);
}

// Round 10
// 13864.355 us; speedup vs baseline: 1.0590x; 1.0590x over previous
//
#include <hip/hip_runtime.h>
#include <stdint.h>
#include <math.h>

#define T_STEPS 1000

typedef __attribute__((ext_vector_type(4))) float f32x4;
typedef __attribute__((ext_vector_type(8))) _Float16 f16x8;
typedef __attribute__((ext_vector_type(4))) int i32x4;
typedef __attribute__((ext_vector_type(4))) unsigned u32x4;

#define C_2M11 4.8828125e-4f         // 2^-11
#define C_2M22 2.384185791015625e-7f // 2^-22
#define F16_MINNORM 6.103515625e-05f

#define VMCNT0() asm volatile("s_waitcnt vmcnt(0)" ::: "memory")
#define DEP4(x)  asm volatile("" : "+v"(x))

__device__ __forceinline__ void split2h(float v, _Float16& hi, _Float16& lo) {
    float av = fabsf(v);
    _Float16 h = (av < F16_MINNORM) ? (_Float16)0.0f : (_Float16)v;
    float r = v - (float)h;
    hi = h;
    lo = (_Float16)(r * 2048.0f);
}
__device__ __forceinline__ unsigned short f2u(_Float16 h) {
    union { _Float16 h; unsigned short s; } u; u.h = h; return u.s;
}
__device__ __forceinline__ _Float16 u2f(unsigned short s) {
    union { unsigned short s; _Float16 h; } u; u.s = s; return u.h;
}
// pack fp32 -> (lo<<16)|hi dword
__device__ __forceinline__ unsigned packv(float v) {
    _Float16 hi, lo;
    split2h(v, hi, lo);
    return (unsigned)f2u(hi) | ((unsigned)f2u(lo) << 16);
}

// ---- MALL (device coherence point) ops — round-6 proven ----
__device__ __forceinline__ u32x4 coh_load4u(const unsigned* p) {
    u32x4 v;
    asm volatile("global_load_dwordx4 %0, %1, off sc0 sc1" : "=v"(v) : "v"(p) : "memory");
    return v;
}
__device__ __forceinline__ f32x4 coh_load4f(const float* p) {
    f32x4 v;
    asm volatile("global_load_dwordx4 %0, %1, off sc0 sc1" : "=v"(v) : "v"(p) : "memory");
    return v;
}
__device__ __forceinline__ void coh_store_u(unsigned* p, unsigned v) {
    asm volatile("global_store_dword %0, %1, off sc0 sc1" :: "v"(p), "v"(v) : "memory");
}
__device__ __forceinline__ void coh_store4f(float* p, f32x4 v) {
    asm volatile("global_store_dwordx4 %0, %1, off sc0 sc1" :: "v"(p), "v"(v) : "memory");
}
__device__ __forceinline__ void coh_store_i(int* p, int v) {
    asm volatile("global_store_dword %0, %1, off sc0 sc1" :: "v"(p), "v"(v) : "memory");
}
__device__ __forceinline__ int coh_load_i_wait(const int* p) {
    int v;
    asm volatile("global_load_dword %0, %1, off sc0 sc1\n\ts_waitcnt vmcnt(0)"
                 : "=v"(v) : "v"(p) : "memory");
    return v;
}
__device__ __forceinline__ void coh_atomic_inc(int* p) {
    int one = 1;
    asm volatile("global_atomic_add %0, %1, off sc1" :: "v"(p), "v"(one) : "memory");
}

// round-6-proven group barrier: drain stores, signal via MALL atomic, poll MALL
__device__ __forceinline__ void group_barrier(int* bar, int target) {
    VMCNT0();
    if (threadIdx.x == 0) coh_atomic_inc(bar);
    int spins = 0;
    while (coh_load_i_wait(bar) < target) {
        if (++spins > (1 << 17)) break;  // hang guard
    }
}

#define MFMAH(a, b, c) __builtin_amdgcn_mfma_f32_16x16x32_f16((a), (b), (c), 0, 0, 0)

// unpack 8 packed dwords -> ah (8 hi halves), al (8 lo halves)
__device__ __forceinline__ void unpack8(const u32x4& d0, const u32x4& d1, f16x8& ah, f16x8& al) {
    union { unsigned u[4]; f16x8 h; } A, L;
    A.u[0] = __builtin_amdgcn_perm(d0[1], d0[0], 0x05040100u);
    A.u[1] = __builtin_amdgcn_perm(d0[3], d0[2], 0x05040100u);
    A.u[2] = __builtin_amdgcn_perm(d1[1], d1[0], 0x05040100u);
    A.u[3] = __builtin_amdgcn_perm(d1[3], d1[2], 0x05040100u);
    L.u[0] = __builtin_amdgcn_perm(d0[1], d0[0], 0x07060302u);
    L.u[1] = __builtin_amdgcn_perm(d0[3], d0[2], 0x07060302u);
    L.u[2] = __builtin_amdgcn_perm(d1[1], d1[0], 0x07060302u);
    L.u[3] = __builtin_amdgcn_perm(d1[3], d1[2], 0x07060302u);
    ah = A.h;
    al = L.h;
}

// ---------------- prep kernels ----------------
__global__ void scalars_kernel(float* As, float* Bc, float* Dc) {
    if (threadIdx.x == 0 && blockIdx.x == 0) {
        float acp = 1.0f, ac_prev = 1.0f;
        for (int t = 0; t < T_STEPS; ++t) {
            float beta = (float)(1.0e-4 + (double)t * ((0.02 - 1.0e-4) / 999.0));
            acp = acp * (1.0f - beta);
            int i = (T_STEPS - 1) - t;
            As[i] = sqrtf(acp);
            Bc[i] = sqrtf(1.0f - acp);
            Dc[i] = sqrtf(1.0f - ac_prev) + sqrtf(beta);
            ac_prev = acp;
        }
    }
}
__global__ void zero_kernel(int* p, int n) {
    int i = blockIdx.x * 64 + threadIdx.x;
    if (i < n) coh_store_i(p + i, 0);
}
__global__ __launch_bounds__(256) void feats_kernel(const float* tw1, const float* tb1, float* s) {
    int idx = blockIdx.x * 256 + threadIdx.x;
    if (idx < T_STEPS * 512) {
        int t = idx >> 9, m = idx & 511;
        float a = (float)t * tw1[m] + tb1[m];
        s[idx] = a / (1.0f + expf(-a));
    }
}
__global__ __launch_bounds__(256) void gemm_kernel(const float* A, const float* B,
                                                   const float* bias, float* C, int M) {
    __shared__ float Asm[16][68];
    __shared__ float Bsm[16][68];
    int tx = threadIdx.x & 15, ty = threadIdx.x >> 4;
    int m0 = blockIdx.x * 64, n0 = blockIdx.y * 64;
    float acc[4][4] = {};
    for (int k0 = 0; k0 < 512; k0 += 16) {
        for (int l = 0; l < 4; ++l) {
            int e = threadIdx.x + l * 256;
            int mm = e >> 4, kk = e & 15;
            Asm[kk][mm] = (m0 + mm < M) ? A[(size_t)(m0 + mm) * 512 + k0 + kk] : 0.0f;
            int nn = e & 63, kk2 = e >> 6;
            Bsm[kk2][nn] = B[(size_t)(k0 + kk2) * 512 + n0 + nn];
        }
        __syncthreads();
        for (int kk = 0; kk < 16; ++kk) {
            float a[4], b[4];
            for (int i = 0; i < 4; ++i) a[i] = Asm[kk][ty * 4 + i];
            for (int j = 0; j < 4; ++j) b[j] = Bsm[kk][tx * 4 + j];
            for (int i = 0; i < 4; ++i)
                for (int j = 0; j < 4; ++j) acc[i][j] += a[i] * b[j];
        }
        __syncthreads();
    }
    for (int i = 0; i < 4; ++i) {
        int m = m0 + ty * 4 + i;
        if (m < M)
            for (int j = 0; j < 4; ++j) {
                int n = n0 + tx * 4 + j;
                C[(size_t)m * 512 + n] = acc[i][j] + bias[n];
            }
    }
}
__global__ __launch_bounds__(256) void tpack_kernel(const float* w, short* ph, short* pl) {
    int p = blockIdx.x * 256 + threadIdx.x;
    if (p < 512 * 512) {
        int chunk = p >> 9, inch = p & 511;
        int n = (chunk >> 4) * 16 + (inch >> 5);
        int k = (chunk & 15) * 32 + (inch & 31);
        float v = w[(size_t)k * 512 + n];
        _Float16 hi, lo;
        split2h(v, hi, lo);
        ph[p] = (short)f2u(hi);
        pl[p] = (short)f2u(lo);
    }
}

// ---------------- main loop: 256 blocks x 64 threads ----------------
__global__ __launch_bounds__(64, 1) void diffusion_main(
    const float* x0,
    const short* w1h_, const short* w1l_,
    const short* w2h_, const short* w2l_,
    unsigned* xg, unsigned* hg,
    float* hid_d, float* hid_e, int* ctr,
    const float* tep, const float* nb2,
    const float* As, const float* Bc, const float* Dc,
    const float* dw1, const float* db1, const float* dw2, const float* db2,
    const float* ew1, const float* eb1, const float* ew2, const float* eb2,
    float* out) {

    __shared__ short wlds[32768];  // [0,16384): W1hi slice, [16384,32768): W2hi slice

    const int bid = blockIdx.x;
    const int rg = ((bid & 7) << 1) | (bid >> 7);
    const int cg = (bid >> 3) & 15;
    const int lane = threadIdx.x;
    const int l15 = lane & 15, lg = lane >> 4;
    const int aoff = l15 * 32 + lg * 8;     // element offset within a 512-elem chunk
    const int b0 = rg * 16;
    int* bar = ctr + rg * 32;

    const short* w1hS = w1h_ + (size_t)cg * 16384;
    const short* w1lS = w1l_ + (size_t)cg * 16384;
    const short* w2hS = w2h_ + (size_t)cg * 16384;
    const short* w2lS = w2l_ + (size_t)cg * 16384;

    // one-time: hi-limb weight slices into LDS (plain cached loads)
    {
        const i32x4* s1 = (const i32x4*)w1hS;
        const i32x4* s2 = (const i32x4*)w2hS;
        i32x4* d = (i32x4*)wlds;
        for (int e = lane; e < 2048; e += 64) d[e] = s1[e];
        for (int e = lane; e < 2048; e += 64) d[2048 + e] = s2[e];
    }
    __syncthreads();

    unsigned* xgR = xg + rg * 8192;   // [16 chunks][16 rows][32 cols] packed dwords
    unsigned* hgR = hg + rg * 8192;

    // init x slice + publish packed (coherence-point dword stores, line-coalesced)
    float xr[2][4], nb2r[2];
    for (int nt = 0; nt < 2; ++nt) {
        int n = cg * 32 + nt * 16 + l15;
        nb2r[nt] = nb2[n];
        for (int r = 0; r < 4; ++r) {
            float v = x0[(size_t)(b0 + lg * 4 + r) * 512 + n];
            xr[nt][r] = v;
            int o = cg * 512 + (lg * 4 + r) * 32 + nt * 16 + l15;
            coh_store_u(xgR + o, packv(v));
        }
    }
    int seq = 1;
    group_barrier(bar, 16 * seq); ++seq;

#pragma unroll 1
    for (int i = 0; i < T_STEPS; ++i) {
        const int t = (T_STEPS - 1) - i;
        float tep_r[2];
        tep_r[0] = tep[(size_t)t * 512 + cg * 32 + l15];
        tep_r[1] = tep[(size_t)t * 512 + cg * 32 + 16 + l15];
        const float a_s = As[i], bc = Bc[i], dc = Dc[i];

        // ---- GEMM1: h_slice = relu(x @ W1slice + tep) ----
        f32x4 a0[2], a1[2], a2[2];
#pragma unroll
        for (int nt = 0; nt < 2; ++nt) {
            a0[nt] = (f32x4){0.f, 0.f, 0.f, 0.f};
            a1[nt] = (f32x4){0.f, 0.f, 0.f, 0.f};
            a2[nt] = (f32x4){0.f, 0.f, 0.f, 0.f};
        }
        {
            u32x4 d0[16], d1[16];
#pragma unroll
            for (int kb = 0; kb < 16; ++kb) {
                d0[kb] = coh_load4u(xgR + kb * 512 + aoff);
                d1[kb] = coh_load4u(xgR + kb * 512 + aoff + 4);
            }
            VMCNT0();
#pragma unroll
            for (int kb = 0; kb < 16; ++kb) { DEP4(d0[kb]); DEP4(d1[kb]); }
#pragma unroll
            for (int kb = 0; kb < 16; ++kb) {
                f16x8 ah, al;
                unpack8(d0[kb], d1[kb], ah, al);
#pragma unroll
                for (int nt = 0; nt < 2; ++nt) {
                    f16x8 bh = *(const f16x8*)(&wlds[(nt * 16 + kb) * 512 + aoff]);
                    f16x8 bl = *(const f16x8*)(w1lS + (nt * 16 + kb) * 512 + aoff);
                    a0[nt] = MFMAH(ah, bh, a0[nt]);
                    a1[nt] = MFMAH(ah, bl, a1[nt]);
                    a1[nt] = MFMAH(al, bh, a1[nt]);
                    a2[nt] = MFMAH(al, bl, a2[nt]);
                }
            }
        }
#pragma unroll
        for (int nt = 0; nt < 2; ++nt)
#pragma unroll
            for (int r = 0; r < 4; ++r) {
                float hv = a0[nt][r] + a1[nt][r] * C_2M11 + a2[nt][r] * C_2M22 + tep_r[nt];
                hv = hv > 0.f ? hv : 0.f;
                int o = cg * 512 + (lg * 4 + r) * 32 + nt * 16 + l15;
                coh_store_u(hgR + o, packv(hv));
            }
        group_barrier(bar, 16 * seq); ++seq;

        // ---- GEMM2: eps_slice = h @ W2slice + nb2; x update ----
#pragma unroll
        for (int nt = 0; nt < 2; ++nt) {
            a0[nt] = (f32x4){0.f, 0.f, 0.f, 0.f};
            a1[nt] = (f32x4){0.f, 0.f, 0.f, 0.f};
            a2[nt] = (f32x4){0.f, 0.f, 0.f, 0.f};
        }
        {
            u32x4 d0[16], d1[16];
#pragma unroll
            for (int kb = 0; kb < 16; ++kb) {
                d0[kb] = coh_load4u(hgR + kb * 512 + aoff);
                d1[kb] = coh_load4u(hgR + kb * 512 + aoff + 4);
            }
            VMCNT0();
#pragma unroll
            for (int kb = 0; kb < 16; ++kb) { DEP4(d0[kb]); DEP4(d1[kb]); }
#pragma unroll
            for (int kb = 0; kb < 16; ++kb) {
                f16x8 ah, al;
                unpack8(d0[kb], d1[kb], ah, al);
#pragma unroll
                for (int nt = 0; nt < 2; ++nt) {
                    f16x8 bh = *(const f16x8*)(&wlds[16384 + (nt * 16 + kb) * 512 + aoff]);
                    f16x8 bl = *(const f16x8*)(w2lS + (nt * 16 + kb) * 512 + aoff);
                    a0[nt] = MFMAH(ah, bh, a0[nt]);
                    a1[nt] = MFMAH(ah, bl, a1[nt]);
                    a1[nt] = MFMAH(al, bh, a1[nt]);
                    a2[nt] = MFMAH(al, bl, a2[nt]);
                }
            }
        }
#pragma unroll
        for (int nt = 0; nt < 2; ++nt)
#pragma unroll
            for (int r = 0; r < 4; ++r) {
                float eps = a0[nt][r] + a1[nt][r] * C_2M11 + a2[nt][r] * C_2M22 + nb2r[nt];
                float xv = (xr[nt][r] - bc * eps) / a_s + dc * eps;
                xv = fminf(fmaxf(xv, -1000.0f), 1000.0f);
                xr[nt][r] = xv;
                int o = cg * 512 + (lg * 4 + r) * 32 + nt * 16 + l15;
                coh_store_u(xgR + o, packv(xv));
            }
        group_barrier(bar, 16 * seq); ++seq;
    }

    // ---- epilogue ----
#pragma unroll
    for (int nt = 0; nt < 2; ++nt)
#pragma unroll
        for (int r = 0; r < 4; ++r)
            out[(size_t)(b0 + lg * 4 + r) * 515 + 3 + cg * 32 + nt * 16 + l15] = xr[nt][r];

    // head hidden slices: lane -> row m=l15, cols cbase..cbase+3
    {
        const int cbase = cg * 16 + lg * 4;
        float a4d[4] = {0.f, 0.f, 0.f, 0.f};
        float a4e[4] = {0.f, 0.f, 0.f, 0.f};
#pragma unroll 1
        for (int kb = 0; kb < 16; ++kb) {
            u32x4 dv[8];
#pragma unroll
            for (int q = 0; q < 8; ++q)
                dv[q] = coh_load4u(xgR + kb * 512 + l15 * 32 + q * 4);
            VMCNT0();
#pragma unroll
            for (int q = 0; q < 8; ++q) { DEP4(dv[q]); }
#pragma unroll
            for (int q = 0; q < 8; ++q)
#pragma unroll
                for (int jj = 0; jj < 4; ++jj) {
                    unsigned u = dv[q][jj];
                    float xv = (float)u2f((unsigned short)(u & 0xFFFFu))
                             + (float)u2f((unsigned short)(u >> 16)) * C_2M11;
                    int k = kb * 32 + q * 4 + jj;
                    f32x4 wd = *(const f32x4*)(dw1 + (size_t)k * 256 + cbase);
                    f32x4 we = *(const f32x4*)(ew1 + (size_t)k * 256 + cbase);
#pragma unroll
                    for (int j = 0; j < 4; ++j) {
                        a4d[j] += xv * wd[j];
                        a4e[j] += xv * we[j];
                    }
                }
        }
        f32x4 hd, he;
#pragma unroll
        for (int j = 0; j < 4; ++j) {
            float hdv = a4d[j] + db1[cbase + j];
            float hev = a4e[j] + eb1[cbase + j];
            hd[j] = hdv > 0.f ? hdv : 0.f;
            he[j] = hev > 0.f ? hev : 0.f;
        }
        coh_store4f(hid_d + rg * 4096 + l15 * 256 + cbase, hd);
        coh_store4f(hid_e + rg * 4096 + l15 * 256 + cbase, he);
    }
    group_barrier(bar, 16 * seq); ++seq;

    if (cg == 0) {
        f32x4 hd4[16], he4[16];
#pragma unroll
        for (int q = 0; q < 16; ++q) {
            hd4[q] = coh_load4f(hid_d + rg * 4096 + l15 * 256 + lg * 64 + q * 4);
            he4[q] = coh_load4f(hid_e + rg * 4096 + l15 * 256 + lg * 64 + q * 4);
        }
        VMCNT0();
#pragma unroll
        for (int q = 0; q < 16; ++q) { DEP4(hd4[q]); DEP4(he4[q]); }
        float sd = 0.f, se1 = 0.f, se2 = 0.f;
#pragma unroll
        for (int q = 0; q < 16; ++q)
#pragma unroll
            for (int j = 0; j < 4; ++j) {
                int c = lg * 64 + q * 4 + j;
                sd += hd4[q][j] * dw2[c];
                se1 += he4[q][j] * ew2[2 * c];
                se2 += he4[q][j] * ew2[2 * c + 1];
            }
        sd += __shfl_xor(sd, 16); sd += __shfl_xor(sd, 32);
        se1 += __shfl_xor(se1, 16); se1 += __shfl_xor(se1, 32);
        se2 += __shfl_xor(se2, 16); se2 += __shfl_xor(se2, 32);
        if (lg == 0) {
            out[(size_t)(b0 + l15) * 515 + 0] = sd + db2[0];
            out[(size_t)(b0 + l15) * 515 + 1] = se1 + eb2[0];
            out[(size_t)(b0 + l15) * 515 + 2] = se2 + eb2[1];
        }
    }
}

extern "C" void kernel_launch(void* const* d_in, const int* in_sizes, int n_in,
                              void* d_out, int out_size, void* d_ws, size_t ws_size,
                              hipStream_t stream) {
    const float* x0  = (const float*)d_in[0];
    const float* tw1 = (const float*)d_in[1];
    const float* tb1 = (const float*)d_in[2];
    const float* tw2 = (const float*)d_in[3];
    const float* tb2 = (const float*)d_in[4];
    const float* nw1 = (const float*)d_in[5];
    const float* nb1 = (const float*)d_in[6];
    const float* nw2 = (const float*)d_in[7];
    const float* nb2 = (const float*)d_in[8];
    const float* dw1 = (const float*)d_in[9];
    const float* db1 = (const float*)d_in[10];
    const float* dw2 = (const float*)d_in[11];
    const float* db2 = (const float*)d_in[12];
    const float* ew1 = (const float*)d_in[13];
    const float* eb1 = (const float*)d_in[14];
    const float* ew2 = (const float*)d_in[15];
    const float* eb2 = (const float*)d_in[16];
    float* out = (float*)d_out;

    float* ws    = (float*)d_ws;
    float* sfeat = ws;                   // 512000 f
    float* te    = sfeat + 512000;
    float* tep   = te + 512000;
    float* Asv   = tep + 512000;         // 1024 f each
    float* Bcv   = Asv + 1024;
    float* Dcv   = Bcv + 1024;
    short* w1h   = (short*)(Dcv + 1024); // 4 planes x 262144 shorts
    short* w1l   = w1h + 262144;
    short* w2h   = w1l + 262144;
    short* w2l   = w2h + 262144;
    unsigned* xgp = (unsigned*)(w2l + 262144); // 2 packed planes x 131072 dwords
    unsigned* hgp = xgp + 131072;
    float* hid_d = (float*)(hgp + 131072);     // 65536 f each
    float* hid_e = hid_d + 65536;
    int*   ctr   = (int*)(hid_e + 65536);      // 512 ints

    hipLaunchKernelGGL(scalars_kernel, dim3(1), dim3(64), 0, stream, Asv, Bcv, Dcv);
    hipLaunchKernelGGL(zero_kernel, dim3(8), dim3(64), 0, stream, ctr, 512);
    hipLaunchKernelGGL(feats_kernel, dim3(2000), dim3(256), 0, stream, tw1, tb1, sfeat);
    hipLaunchKernelGGL(gemm_kernel, dim3(16, 8), dim3(256), 0, stream, sfeat, tw2, tb2, te, 1000);
    hipLaunchKernelGGL(gemm_kernel, dim3(16, 8), dim3(256), 0, stream, te, nw1 + 512 * 512, nb1, tep, 1000);
    hipLaunchKernelGGL(tpack_kernel, dim3(1024), dim3(256), 0, stream, nw1, w1h, w1l);
    hipLaunchKernelGGL(tpack_kernel, dim3(1024), dim3(256), 0, stream, nw2, w2h, w2l);
    hipLaunchKernelGGL(diffusion_main, dim3(256), dim3(64), 0, stream,
                       x0, w1h, w1l, w2h, w2l,
                       xgp, hgp, hid_d, hid_e, ctr,
                       tep, nb2, Asv, Bcv, Dcv,
                       dw1, db1, dw2, db2, ew1, eb1, ew2, eb2, out);
}